// Round 9
// baseline (634.919 us; speedup 1.0000x reference)
//
#include <hip/hip_runtime.h>

#define NN 50000
#define CAP 32          // per-node bin capacity; overflow handled correctly
#define OVF_CAP 4096
#define RANGES 32       // node ranges per relation (LDS-staged bin_fill)
#define RW 1563         // ceil(NN / RANGES)

__device__ __forceinline__ unsigned short f2bf(float f) {
    unsigned u = __float_as_uint(f);
    u += 0x7fffu + ((u >> 16) & 1u);           // round-to-nearest-even
    return (unsigned short)(u >> 16);
}
__device__ __forceinline__ float bf2f(unsigned short u) {
    return __uint_as_float(((unsigned)u) << 16);
}

// fp32 -> bf16 row copy (n4 = count of float4s)
__global__ __launch_bounds__(256) void to_bf16(
    const float* __restrict__ in, unsigned short* __restrict__ out, int n4)
{
    int stride = gridDim.x * blockDim.x;
    for (int i = blockIdx.x * blockDim.x + threadIdx.x; i < n4; i += stride) {
        float4 v = ((const float4*)in)[i];
        ushort4 o;
        o.x = f2bf(v.x); o.y = f2bf(v.y); o.z = f2bf(v.z); o.w = f2bf(v.w);
        ((ushort4*)out)[i] = o;
    }
}

// LDS-staged bin fill. R4-R8 lesson: scattered 2-4B global stores/atomics
// plateau at ~1.5 TB/s with ~10x write amplification no matter the sharding
// (R8: ushort bins halved footprint, WRITE barely moved). So: stage the
// whole scatter in LDS. Block = (relation, node-range of 1563); scan the
// relation's dst list (streaming), LDS-atomic rank, LDS-store src; then one
// fully-coalesced writeout of bins+deg. Zero scattered global stores.
// Also writes every deg entry -> no deg memset needed.
__global__ __launch_bounds__(1024, 1) void bin_fill(
    const int* __restrict__ ei0, int E0,
    const int* __restrict__ ei1, int E1,
    int* __restrict__ deg, unsigned short* __restrict__ bins,
    int2* __restrict__ ovf, int* __restrict__ ovf_cnt)
{
    __shared__ unsigned short sbins[RW * CAP];   // 100,032 B
    __shared__ unsigned int   sdeg[RW];          // 6,252 B

    int rel = blockIdx.x >> 5;          // 64 blocks: 0-31 rel0, 32-63 rel1
    int rng = blockIdx.x & 31;
    const int* ei = rel ? ei1 : ei0;
    int E = rel ? E1 : E0;
    int lo = rng * RW;
    int n_local = min(RW, NN - lo);
    int baseT = rel * NN + lo;

    int tid = threadIdx.x;
    for (int i = tid; i < RW; i += 1024) sdeg[i] = 0;
    __syncthreads();

    for (int t = tid; t < E; t += 1024) {
        int dstv = ei[E + t];
        unsigned local = (unsigned)(dstv - lo);
        if (local < (unsigned)n_local) {
            int s = ei[t];
            unsigned r = atomicAdd(&sdeg[local], 1u);
            if (r < CAP) {
                sbins[local * CAP + r] = (unsigned short)s;
            } else {
                int o = atomicAdd(ovf_cnt, 1);
                if (o < OVF_CAP) ovf[o] = make_int2(baseT + (int)local, s);
            }
        }
    }
    __syncthreads();

    unsigned int* gb = (unsigned int*)(bins + (size_t)baseT * CAP);
    const unsigned int* sb = (const unsigned int*)sbins;
    int nwords = n_local * (CAP / 2);
    for (int i = tid; i < nwords; i += 1024) gb[i] = sb[i];
    for (int i = tid; i < n_local; i += 1024) deg[baseT + i] = (int)sdeg[i];
}

// One (rel,node) task per wave; paired gathers: lane loads a uint (2 bf16
// feats), low half-wave covers src 2q, high half src 2q+1 -> 2 rows per
// gather instruction at 4B/lane (was 1 row at 2B/lane). 4 chains of ILP.
__global__ __launch_bounds__(256) void aggregate(
    const unsigned short* __restrict__ bins, const int* __restrict__ deg,
    const unsigned short* __restrict__ hb, float* __restrict__ agg)
{
    int lane = threadIdx.x & 63;
    int half = lane >> 5;
    int p = lane & 31;                 // feature-pair index
    int wid = (blockIdx.x * blockDim.x + threadIdx.x) >> 6;
    int nwaves = (gridDim.x * blockDim.x) >> 6;
    const unsigned int* hb32 = (const unsigned int*)hb;

    for (int task = wid; task < 2 * NN; task += nwaves) {
        int d = deg[task];
        int m = min(d, CAP);
        int idx = 0;
        if (lane < m) idx = bins[(size_t)task * CAP + lane];
        float a00=0.f,a01=0.f, a10=0.f,a11=0.f, a20=0.f,a21=0.f, a30=0.f,a31=0.f;
        int F = m >> 1;                // complete pair-steps
        int q = 0;
        for (; q + 4 <= F; q += 4) {
            int s0 = __shfl(idx, 2*(q+0) + half);
            int s1 = __shfl(idx, 2*(q+1) + half);
            int s2 = __shfl(idx, 2*(q+2) + half);
            int s3 = __shfl(idx, 2*(q+3) + half);
            unsigned u0 = hb32[(size_t)s0 * 32 + p];
            unsigned u1 = hb32[(size_t)s1 * 32 + p];
            unsigned u2 = hb32[(size_t)s2 * 32 + p];
            unsigned u3 = hb32[(size_t)s3 * 32 + p];
            a00 += __uint_as_float(u0 << 16); a01 += __uint_as_float(u0 & 0xffff0000u);
            a10 += __uint_as_float(u1 << 16); a11 += __uint_as_float(u1 & 0xffff0000u);
            a20 += __uint_as_float(u2 << 16); a21 += __uint_as_float(u2 & 0xffff0000u);
            a30 += __uint_as_float(u3 << 16); a31 += __uint_as_float(u3 & 0xffff0000u);
        }
        for (; q < F; ++q) {
            int s = __shfl(idx, 2*q + half);
            unsigned u = hb32[(size_t)s * 32 + p];
            a00 += __uint_as_float(u << 16); a01 += __uint_as_float(u & 0xffff0000u);
        }
        if (m & 1) {
            int s = __shfl(idx, m - 1);
            if (half == 0) {
                unsigned u = hb32[(size_t)s * 32 + p];
                a00 += __uint_as_float(u << 16); a01 += __uint_as_float(u & 0xffff0000u);
            }
        }
        float s0 = (a00 + a10) + (a20 + a30);
        float s1 = (a01 + a11) + (a21 + a31);
        s0 += __shfl_xor(s0, 32);
        s1 += __shfl_xor(s1, 32);
        if (half == 0) {
            float inv = 1.0f / (float)max(d, 1);
            *(float2*)&agg[(size_t)task * 64 + 2 * p] = make_float2(s0 * inv, s1 * inv);
        }
    }
}

// Overflow fixup on fp32 h (tiny work; agg stays fp32 so atomicAdd works).
__global__ __launch_bounds__(256) void ovf_fix(
    const int2* __restrict__ ovf, const int* __restrict__ ovf_cnt,
    const int* __restrict__ deg, const float* __restrict__ h,
    float* __restrict__ agg)
{
    int cnt = min(*ovf_cnt, OVF_CAP);
    int total = cnt * 64;
    int stride = gridDim.x * blockDim.x;
    for (int t = blockIdx.x * blockDim.x + threadIdx.x; t < total; t += stride) {
        int e = t >> 6, f = t & 63;
        int2 v = ovf[e];
        float val = h[(size_t)v.y * 64 + f] / (float)max(deg[v.x], 1);
        atomicAdd(&agg[(size_t)v.x * 64 + f], val);
    }
}

// hout = relu(mean0@Wl0 + mean1@Wl1 + self@(Wr0+Wr1) + (b0+b1))
#define RST 132
__global__ __launch_bounds__(256) void layer_gemm(
    const float* __restrict__ agg0, const float* __restrict__ agg1,
    const unsigned short* __restrict__ selfb,
    const float* __restrict__ Wl0, const float* __restrict__ Wl1,
    const float* __restrict__ Wr0, const float* __restrict__ Wr1,
    const float* __restrict__ b0, const float* __restrict__ b1,
    float* __restrict__ hout, unsigned short* __restrict__ hb16)
{
    __shared__ float Wch[64 * 64];
    __shared__ float rowsT[64 * RST];
    __shared__ float bias[64];

    int tid = threadIdx.x;
    int base = blockIdx.x * 128;
    if (tid < 64) bias[tid] = b0[tid] + b1[tid];

    int j8 = (tid & 7) * 8;
    int n4 = (tid >> 3) * 4;

    float acc[4][8];
    #pragma unroll
    for (int i = 0; i < 4; i++)
        #pragma unroll
        for (int c = 0; c < 8; c++) acc[i][c] = 0.f;

    for (int chunk = 0; chunk < 3; chunk++) {
        const float* W = (chunk == 0) ? Wl0 : (chunk == 1) ? Wl1 : Wr0;
        __syncthreads();
        #pragma unroll
        for (int r = 0; r < 4; r++) {
            int i = tid + 256 * r;
            float4 w = *(const float4*)&W[i * 4];
            if (chunk == 2) {
                float4 w2 = *(const float4*)&Wr1[i * 4];
                w.x += w2.x; w.y += w2.y; w.z += w2.z; w.w += w2.w;
            }
            *(float4*)&Wch[i * 4] = w;
        }
        if (chunk < 2) {
            const float* src = (chunk == 0) ? agg0 : agg1;
            #pragma unroll
            for (int r = 0; r < 8; r++) {
                int i = tid + 256 * r;
                int node = i >> 4;
                int k4 = (i & 15) * 4;
                float4 v = make_float4(0.f, 0.f, 0.f, 0.f);
                int g = base + node;
                if (g < NN) v = *(const float4*)&src[(size_t)g * 64 + k4];
                rowsT[(k4 + 0) * RST + node] = v.x;
                rowsT[(k4 + 1) * RST + node] = v.y;
                rowsT[(k4 + 2) * RST + node] = v.z;
                rowsT[(k4 + 3) * RST + node] = v.w;
            }
        } else {
            #pragma unroll
            for (int r = 0; r < 8; r++) {
                int i = tid + 256 * r;
                int node = i >> 4;
                int k4 = (i & 15) * 4;
                int g = base + node;
                ushort4 u = make_ushort4(0, 0, 0, 0);
                if (g < NN) u = *(const ushort4*)&selfb[(size_t)g * 64 + k4];
                rowsT[(k4 + 0) * RST + node] = bf2f(u.x);
                rowsT[(k4 + 1) * RST + node] = bf2f(u.y);
                rowsT[(k4 + 2) * RST + node] = bf2f(u.z);
                rowsT[(k4 + 3) * RST + node] = bf2f(u.w);
            }
        }
        __syncthreads();
        #pragma unroll 4
        for (int k = 0; k < 64; k++) {
            float4 wa = *(const float4*)&Wch[k * 64 + j8];
            float4 wb = *(const float4*)&Wch[k * 64 + j8 + 4];
            float4 rv = *(const float4*)&rowsT[k * RST + n4];
            float w[8] = {wa.x, wa.y, wa.z, wa.w, wb.x, wb.y, wb.z, wb.w};
            float rr[4] = {rv.x, rv.y, rv.z, rv.w};
            #pragma unroll
            for (int i = 0; i < 4; i++)
                #pragma unroll
                for (int c = 0; c < 8; c++)
                    acc[i][c] = fmaf(rr[i], w[c], acc[i][c]);
        }
    }

    #pragma unroll
    for (int i = 0; i < 4; i++) {
        int g = base + n4 + i;
        if (g < NN) {
            float4 o1, o2;
            o1.x = fmaxf(acc[i][0] + bias[j8 + 0], 0.f);
            o1.y = fmaxf(acc[i][1] + bias[j8 + 1], 0.f);
            o1.z = fmaxf(acc[i][2] + bias[j8 + 2], 0.f);
            o1.w = fmaxf(acc[i][3] + bias[j8 + 3], 0.f);
            o2.x = fmaxf(acc[i][4] + bias[j8 + 4], 0.f);
            o2.y = fmaxf(acc[i][5] + bias[j8 + 5], 0.f);
            o2.z = fmaxf(acc[i][6] + bias[j8 + 6], 0.f);
            o2.w = fmaxf(acc[i][7] + bias[j8 + 7], 0.f);
            *(float4*)&hout[(size_t)g * 64 + j8]     = o1;
            *(float4*)&hout[(size_t)g * 64 + j8 + 4] = o2;
            if (hb16) {
                ushort4 p0, p1;
                p0.x = f2bf(o1.x); p0.y = f2bf(o1.y); p0.z = f2bf(o1.z); p0.w = f2bf(o1.w);
                p1.x = f2bf(o2.x); p1.y = f2bf(o2.y); p1.z = f2bf(o2.z); p1.w = f2bf(o2.w);
                *(ushort4*)&hb16[(size_t)g * 64 + j8]     = p0;
                *(ushort4*)&hb16[(size_t)g * 64 + j8 + 4] = p1;
            }
        }
    }
}

// out[i,:32] = h[i,:64] @ W + b
__global__ __launch_bounds__(256) void final_gemm(
    const float* __restrict__ h, const float* __restrict__ W,
    const float* __restrict__ b, float* __restrict__ out)
{
    __shared__ float Ws[64 * 32];
    __shared__ float bs[32];
    __shared__ float rows[8][64];

    int tid = threadIdx.x;
    for (int i = tid; i < 2048; i += 256) Ws[i] = W[i];
    if (tid < 32) bs[tid] = b[tid];

    int j = tid & 31;
    int nl = tid >> 5;

    for (int base = blockIdx.x * 8; base < NN; base += gridDim.x * 8) {
        __syncthreads();
        if (tid < 128) {
            int n = tid >> 4, kq = tid & 15;
            int node = base + n;
            float4 v = make_float4(0.f, 0.f, 0.f, 0.f);
            if (node < NN) v = *(const float4*)&h[(size_t)node * 64 + kq * 4];
            *(float4*)&rows[n][kq * 4] = v;
        }
        __syncthreads();

        int node = base + nl;
        if (node < NN) {
            float acc = bs[j];
            #pragma unroll
            for (int k = 0; k < 64; k += 4) {
                float4 rv = *(const float4*)&rows[nl][k];
                acc = fmaf(rv.x, Ws[(k + 0) * 32 + j], acc);
                acc = fmaf(rv.y, Ws[(k + 1) * 32 + j], acc);
                acc = fmaf(rv.z, Ws[(k + 2) * 32 + j], acc);
                acc = fmaf(rv.w, Ws[(k + 3) * 32 + j], acc);
            }
            out[(size_t)node * 32 + j] = acc;
        }
    }
}

extern "C" void kernel_launch(void* const* d_in, const int* in_sizes, int n_in,
                              void* d_out, int out_size, void* d_ws, size_t ws_size,
                              hipStream_t stream)
{
    const float* x    = (const float*)d_in[0];
    const int*   ei0  = (const int*)d_in[1];
    const int*   ei1  = (const int*)d_in[2];
    const float* Wl   = (const float*)d_in[3];   // [2,2,64,64]
    const float* Wr   = (const float*)d_in[4];   // [2,2,64,64]
    const float* bl   = (const float*)d_in[5];   // [2,2,64]
    const float* linW = (const float*)d_in[6];   // [64,32]
    const float* linb = (const float*)d_in[7];   // [32]
    float* out = (float*)d_out;

    int E0 = in_sizes[1] / 2;
    int E1 = in_sizes[2] / 2;

    // Workspace (large, aligned buffers first):
    // [bins 6.4MB us | agg 25.6MB f | h1 12.8MB f | xb 6.4MB us | h1b 6.4MB us |
    //  deg 400KB | ovf_cnt(pad 32) | ovf]  ~58 MB
    unsigned short* bins = (unsigned short*)d_ws;
    float* agg  = (float*)(bins + (size_t)2 * NN * CAP);
    float* agg0 = agg;
    float* agg1 = agg + (size_t)NN * 64;
    float* h1   = agg + (size_t)2 * NN * 64;
    unsigned short* xb  = (unsigned short*)(h1 + (size_t)NN * 64);
    unsigned short* h1b = xb + (size_t)NN * 64;
    int*  deg     = (int*)(h1b + (size_t)NN * 64);
    int*  ovf_cnt = deg + 2 * NN;
    int2* ovf     = (int2*)(ovf_cnt + 8);

    dim3 blk(256);
    int ggrid = (NN + 127) / 128;   // 391

    (void)hipMemsetAsync(ovf_cnt, 0, 32, stream);   // deg written fully by bin_fill
    bin_fill<<<64, dim3(1024), 0, stream>>>(ei0, E0, ei1, E1, deg, bins, ovf, ovf_cnt);
    to_bf16<<<1024, blk, 0, stream>>>(x, xb, NN * 16);

    // ---- Layer 0 (gather from xb, self from xb) ----
    aggregate<<<4096, blk, 0, stream>>>(bins, deg, xb, agg);
    ovf_fix<<<64, blk, 0, stream>>>(ovf, ovf_cnt, deg, x, agg);
    layer_gemm<<<ggrid, blk, 0, stream>>>(agg0, agg1, xb,
        Wl + 0, Wl + 4096, Wr + 0, Wr + 4096, bl + 0, bl + 64, h1, h1b);

    // ---- Layer 1 (gather from h1b, self from h1b, hout in h1) ----
    aggregate<<<4096, blk, 0, stream>>>(bins, deg, h1b, agg);
    ovf_fix<<<64, blk, 0, stream>>>(ovf, ovf_cnt, deg, h1, agg);
    layer_gemm<<<ggrid, blk, 0, stream>>>(agg0, agg1, h1b,
        Wl + 8192, Wl + 12288, Wr + 8192, Wr + 12288, bl + 128, bl + 192, h1, (unsigned short*)nullptr);

    // ---- Final projection ----
    final_gemm<<<768, blk, 0, stream>>>(h1, linW, linb, out);
}

// Round 10
// 301.076 us; speedup vs baseline: 2.1088x; 2.1088x over previous
//
#include <hip/hip_runtime.h>

#define NN 50000
#define CAP 32          // per-node bin capacity; overflow handled correctly
#define OVF_CAP 4096
#define SHARD_W 12500   // 4 contiguous node ranges per relation

__device__ __forceinline__ unsigned short f2bf(float f) {
    unsigned u = __float_as_uint(f);
    u += 0x7fffu + ((u >> 16) & 1u);           // round-to-nearest-even
    return (unsigned short)(u >> 16);
}
__device__ __forceinline__ float bf2f(unsigned short u) {
    return __uint_as_float(((unsigned)u) << 16);
}

// fp32 -> bf16 row copy (n4 = count of float4s)
__global__ __launch_bounds__(256) void to_bf16(
    const float* __restrict__ in, unsigned short* __restrict__ out, int n4)
{
    int stride = gridDim.x * blockDim.x;
    for (int i = blockIdx.x * blockDim.x + threadIdx.x; i < n4; i += stride) {
        float4 v = ((const float4*)in)[i];
        ushort4 o;
        o.x = f2bf(v.x); o.y = f2bf(v.y); o.z = f2bf(v.z); o.w = f2bf(v.w);
        ((ushort4*)out)[i] = o;
    }
}

// Range-sharded single-pass bin fill (R7 structure — best measured: 72us at
// ~80% occupancy). Groups 0-3 scan ei0 / own node range [g*12500,(g+1)*12500);
// groups 4-7 same for ei1. ushort bins halve writeback vs int.
// R9's LDS-staged variant cut WRITE 59->6.6MB but serialized on 64 blocks
// (480us) — full-GPU scattered atomics win on wall clock.
__global__ __launch_bounds__(256) void bin_fill(
    const int* __restrict__ ei0, int E0,
    const int* __restrict__ ei1, int E1,
    int* __restrict__ deg, unsigned short* __restrict__ bins,
    int2* __restrict__ ovf, int* __restrict__ ovf_cnt)
{
    int grp  = blockIdx.x & 7;
    int lblk = blockIdx.x >> 3;
    int lgrid = gridDim.x >> 3;
    const int* ei; int E; int baseT;
    if (grp < 4) { ei = ei0; E = E0; baseT = 0; }
    else         { ei = ei1; E = E1; baseT = NN; }
    int want = grp & 3;

    int stride = lgrid * blockDim.x;
    for (int t = lblk * blockDim.x + threadIdx.x; t < E; t += stride) {
        int dstv = ei[E + t];
        if (dstv / SHARD_W == want) {
            int task = baseT + dstv;
            int s = ei[t];
            int r = atomicAdd(&deg[task], 1);
            if (r < CAP) {
                bins[(size_t)task * CAP + r] = (unsigned short)s;
            } else {
                int o = atomicAdd(ovf_cnt, 1);
                if (o < OVF_CAP) ovf[o] = make_int2(task, s);
            }
        }
    }
}

// One (rel,node) task per wave; paired gathers: lane loads a uint (2 bf16
// feats), low half-wave covers src 2q, high half src 2q+1 -> 2 rows per
// gather instruction at 4B/lane. 4 chains of ILP. (R9: halved agg time.)
__global__ __launch_bounds__(256) void aggregate(
    const unsigned short* __restrict__ bins, const int* __restrict__ deg,
    const unsigned short* __restrict__ hb, float* __restrict__ agg)
{
    int lane = threadIdx.x & 63;
    int half = lane >> 5;
    int p = lane & 31;                 // feature-pair index
    int wid = (blockIdx.x * blockDim.x + threadIdx.x) >> 6;
    int nwaves = (gridDim.x * blockDim.x) >> 6;
    const unsigned int* hb32 = (const unsigned int*)hb;

    for (int task = wid; task < 2 * NN; task += nwaves) {
        int d = deg[task];
        int m = min(d, CAP);
        int idx = 0;
        if (lane < m) idx = bins[(size_t)task * CAP + lane];
        float a00=0.f,a01=0.f, a10=0.f,a11=0.f, a20=0.f,a21=0.f, a30=0.f,a31=0.f;
        int F = m >> 1;                // complete pair-steps
        int q = 0;
        for (; q + 4 <= F; q += 4) {
            int s0 = __shfl(idx, 2*(q+0) + half);
            int s1 = __shfl(idx, 2*(q+1) + half);
            int s2 = __shfl(idx, 2*(q+2) + half);
            int s3 = __shfl(idx, 2*(q+3) + half);
            unsigned u0 = hb32[(size_t)s0 * 32 + p];
            unsigned u1 = hb32[(size_t)s1 * 32 + p];
            unsigned u2 = hb32[(size_t)s2 * 32 + p];
            unsigned u3 = hb32[(size_t)s3 * 32 + p];
            a00 += __uint_as_float(u0 << 16); a01 += __uint_as_float(u0 & 0xffff0000u);
            a10 += __uint_as_float(u1 << 16); a11 += __uint_as_float(u1 & 0xffff0000u);
            a20 += __uint_as_float(u2 << 16); a21 += __uint_as_float(u2 & 0xffff0000u);
            a30 += __uint_as_float(u3 << 16); a31 += __uint_as_float(u3 & 0xffff0000u);
        }
        for (; q < F; ++q) {
            int s = __shfl(idx, 2*q + half);
            unsigned u = hb32[(size_t)s * 32 + p];
            a00 += __uint_as_float(u << 16); a01 += __uint_as_float(u & 0xffff0000u);
        }
        if (m & 1) {
            int s = __shfl(idx, m - 1);
            if (half == 0) {
                unsigned u = hb32[(size_t)s * 32 + p];
                a00 += __uint_as_float(u << 16); a01 += __uint_as_float(u & 0xffff0000u);
            }
        }
        float s0 = (a00 + a10) + (a20 + a30);
        float s1 = (a01 + a11) + (a21 + a31);
        s0 += __shfl_xor(s0, 32);
        s1 += __shfl_xor(s1, 32);
        if (half == 0) {
            float inv = 1.0f / (float)max(d, 1);
            *(float2*)&agg[(size_t)task * 64 + 2 * p] = make_float2(s0 * inv, s1 * inv);
        }
    }
}

// Overflow fixup on fp32 h (tiny work; agg stays fp32 so atomicAdd works).
__global__ __launch_bounds__(256) void ovf_fix(
    const int2* __restrict__ ovf, const int* __restrict__ ovf_cnt,
    const int* __restrict__ deg, const float* __restrict__ h,
    float* __restrict__ agg)
{
    int cnt = min(*ovf_cnt, OVF_CAP);
    int total = cnt * 64;
    int stride = gridDim.x * blockDim.x;
    for (int t = blockIdx.x * blockDim.x + threadIdx.x; t < total; t += stride) {
        int e = t >> 6, f = t & 63;
        int2 v = ovf[e];
        float val = h[(size_t)v.y * 64 + f] / (float)max(deg[v.x], 1);
        atomicAdd(&agg[(size_t)v.x * 64 + f], val);
    }
}

// hout = relu(mean0@Wl0 + mean1@Wl1 + self@(Wr0+Wr1) + (b0+b1))
#define RST 132
__global__ __launch_bounds__(256) void layer_gemm(
    const float* __restrict__ agg0, const float* __restrict__ agg1,
    const unsigned short* __restrict__ selfb,
    const float* __restrict__ Wl0, const float* __restrict__ Wl1,
    const float* __restrict__ Wr0, const float* __restrict__ Wr1,
    const float* __restrict__ b0, const float* __restrict__ b1,
    float* __restrict__ hout, unsigned short* __restrict__ hb16)
{
    __shared__ float Wch[64 * 64];
    __shared__ float rowsT[64 * RST];
    __shared__ float bias[64];

    int tid = threadIdx.x;
    int base = blockIdx.x * 128;
    if (tid < 64) bias[tid] = b0[tid] + b1[tid];

    int j8 = (tid & 7) * 8;
    int n4 = (tid >> 3) * 4;

    float acc[4][8];
    #pragma unroll
    for (int i = 0; i < 4; i++)
        #pragma unroll
        for (int c = 0; c < 8; c++) acc[i][c] = 0.f;

    for (int chunk = 0; chunk < 3; chunk++) {
        const float* W = (chunk == 0) ? Wl0 : (chunk == 1) ? Wl1 : Wr0;
        __syncthreads();
        #pragma unroll
        for (int r = 0; r < 4; r++) {
            int i = tid + 256 * r;
            float4 w = *(const float4*)&W[i * 4];
            if (chunk == 2) {
                float4 w2 = *(const float4*)&Wr1[i * 4];
                w.x += w2.x; w.y += w2.y; w.z += w2.z; w.w += w2.w;
            }
            *(float4*)&Wch[i * 4] = w;
        }
        if (chunk < 2) {
            const float* src = (chunk == 0) ? agg0 : agg1;
            #pragma unroll
            for (int r = 0; r < 8; r++) {
                int i = tid + 256 * r;
                int node = i >> 4;
                int k4 = (i & 15) * 4;
                float4 v = make_float4(0.f, 0.f, 0.f, 0.f);
                int g = base + node;
                if (g < NN) v = *(const float4*)&src[(size_t)g * 64 + k4];
                rowsT[(k4 + 0) * RST + node] = v.x;
                rowsT[(k4 + 1) * RST + node] = v.y;
                rowsT[(k4 + 2) * RST + node] = v.z;
                rowsT[(k4 + 3) * RST + node] = v.w;
            }
        } else {
            #pragma unroll
            for (int r = 0; r < 8; r++) {
                int i = tid + 256 * r;
                int node = i >> 4;
                int k4 = (i & 15) * 4;
                int g = base + node;
                ushort4 u = make_ushort4(0, 0, 0, 0);
                if (g < NN) u = *(const ushort4*)&selfb[(size_t)g * 64 + k4];
                rowsT[(k4 + 0) * RST + node] = bf2f(u.x);
                rowsT[(k4 + 1) * RST + node] = bf2f(u.y);
                rowsT[(k4 + 2) * RST + node] = bf2f(u.z);
                rowsT[(k4 + 3) * RST + node] = bf2f(u.w);
            }
        }
        __syncthreads();
        #pragma unroll 4
        for (int k = 0; k < 64; k++) {
            float4 wa = *(const float4*)&Wch[k * 64 + j8];
            float4 wb = *(const float4*)&Wch[k * 64 + j8 + 4];
            float4 rv = *(const float4*)&rowsT[k * RST + n4];
            float w[8] = {wa.x, wa.y, wa.z, wa.w, wb.x, wb.y, wb.z, wb.w};
            float rr[4] = {rv.x, rv.y, rv.z, rv.w};
            #pragma unroll
            for (int i = 0; i < 4; i++)
                #pragma unroll
                for (int c = 0; c < 8; c++)
                    acc[i][c] = fmaf(rr[i], w[c], acc[i][c]);
        }
    }

    #pragma unroll
    for (int i = 0; i < 4; i++) {
        int g = base + n4 + i;
        if (g < NN) {
            float4 o1, o2;
            o1.x = fmaxf(acc[i][0] + bias[j8 + 0], 0.f);
            o1.y = fmaxf(acc[i][1] + bias[j8 + 1], 0.f);
            o1.z = fmaxf(acc[i][2] + bias[j8 + 2], 0.f);
            o1.w = fmaxf(acc[i][3] + bias[j8 + 3], 0.f);
            o2.x = fmaxf(acc[i][4] + bias[j8 + 4], 0.f);
            o2.y = fmaxf(acc[i][5] + bias[j8 + 5], 0.f);
            o2.z = fmaxf(acc[i][6] + bias[j8 + 6], 0.f);
            o2.w = fmaxf(acc[i][7] + bias[j8 + 7], 0.f);
            *(float4*)&hout[(size_t)g * 64 + j8]     = o1;
            *(float4*)&hout[(size_t)g * 64 + j8 + 4] = o2;
            if (hb16) {
                ushort4 p0, p1;
                p0.x = f2bf(o1.x); p0.y = f2bf(o1.y); p0.z = f2bf(o1.z); p0.w = f2bf(o1.w);
                p1.x = f2bf(o2.x); p1.y = f2bf(o2.y); p1.z = f2bf(o2.z); p1.w = f2bf(o2.w);
                *(ushort4*)&hb16[(size_t)g * 64 + j8]     = p0;
                *(ushort4*)&hb16[(size_t)g * 64 + j8 + 4] = p1;
            }
        }
    }
}

// out[i,:32] = h[i,:64] @ W + b
__global__ __launch_bounds__(256) void final_gemm(
    const float* __restrict__ h, const float* __restrict__ W,
    const float* __restrict__ b, float* __restrict__ out)
{
    __shared__ float Ws[64 * 32];
    __shared__ float bs[32];
    __shared__ float rows[8][64];

    int tid = threadIdx.x;
    for (int i = tid; i < 2048; i += 256) Ws[i] = W[i];
    if (tid < 32) bs[tid] = b[tid];

    int j = tid & 31;
    int nl = tid >> 5;

    for (int base = blockIdx.x * 8; base < NN; base += gridDim.x * 8) {
        __syncthreads();
        if (tid < 128) {
            int n = tid >> 4, kq = tid & 15;
            int node = base + n;
            float4 v = make_float4(0.f, 0.f, 0.f, 0.f);
            if (node < NN) v = *(const float4*)&h[(size_t)node * 64 + kq * 4];
            *(float4*)&rows[n][kq * 4] = v;
        }
        __syncthreads();

        int node = base + nl;
        if (node < NN) {
            float acc = bs[j];
            #pragma unroll
            for (int k = 0; k < 64; k += 4) {
                float4 rv = *(const float4*)&rows[nl][k];
                acc = fmaf(rv.x, Ws[(k + 0) * 32 + j], acc);
                acc = fmaf(rv.y, Ws[(k + 1) * 32 + j], acc);
                acc = fmaf(rv.z, Ws[(k + 2) * 32 + j], acc);
                acc = fmaf(rv.w, Ws[(k + 3) * 32 + j], acc);
            }
            out[(size_t)node * 32 + j] = acc;
        }
    }
}

extern "C" void kernel_launch(void* const* d_in, const int* in_sizes, int n_in,
                              void* d_out, int out_size, void* d_ws, size_t ws_size,
                              hipStream_t stream)
{
    const float* x    = (const float*)d_in[0];
    const int*   ei0  = (const int*)d_in[1];
    const int*   ei1  = (const int*)d_in[2];
    const float* Wl   = (const float*)d_in[3];   // [2,2,64,64]
    const float* Wr   = (const float*)d_in[4];   // [2,2,64,64]
    const float* bl   = (const float*)d_in[5];   // [2,2,64]
    const float* linW = (const float*)d_in[6];   // [64,32]
    const float* linb = (const float*)d_in[7];   // [32]
    float* out = (float*)d_out;

    int E0 = in_sizes[1] / 2;
    int E1 = in_sizes[2] / 2;

    // Workspace (large, aligned buffers first):
    // [bins 6.4MB us | agg 25.6MB f | h1 12.8MB f | xb 6.4MB us | h1b 6.4MB us |
    //  deg 400KB | ovf_cnt(pad) | ovf]  ~58 MB
    unsigned short* bins = (unsigned short*)d_ws;
    float* agg  = (float*)(bins + (size_t)2 * NN * CAP);
    float* agg0 = agg;
    float* agg1 = agg + (size_t)NN * 64;
    float* h1   = agg + (size_t)2 * NN * 64;
    unsigned short* xb  = (unsigned short*)(h1 + (size_t)NN * 64);
    unsigned short* h1b = xb + (size_t)NN * 64;
    int*  deg     = (int*)(h1b + (size_t)NN * 64);
    int*  ovf_cnt = deg + 2 * NN;
    int2* ovf     = (int2*)(ovf_cnt + 8);

    dim3 blk(256);
    int ggrid = (NN + 127) / 128;   // 391

    (void)hipMemsetAsync(deg, 0, (2 * NN + 8) * sizeof(int), stream);
    bin_fill<<<2048, blk, 0, stream>>>(ei0, E0, ei1, E1, deg, bins, ovf, ovf_cnt);
    to_bf16<<<1024, blk, 0, stream>>>(x, xb, NN * 16);

    // ---- Layer 0 (gather from xb, self from xb) ----
    aggregate<<<4096, blk, 0, stream>>>(bins, deg, xb, agg);
    ovf_fix<<<64, blk, 0, stream>>>(ovf, ovf_cnt, deg, x, agg);
    layer_gemm<<<ggrid, blk, 0, stream>>>(agg0, agg1, xb,
        Wl + 0, Wl + 4096, Wr + 0, Wr + 4096, bl + 0, bl + 64, h1, h1b);

    // ---- Layer 1 (gather from h1b, self from h1b, hout in h1) ----
    aggregate<<<4096, blk, 0, stream>>>(bins, deg, h1b, agg);
    ovf_fix<<<64, blk, 0, stream>>>(ovf, ovf_cnt, deg, h1, agg);
    layer_gemm<<<ggrid, blk, 0, stream>>>(agg0, agg1, h1b,
        Wl + 8192, Wl + 12288, Wr + 8192, Wr + 12288, bl + 128, bl + 192, h1, (unsigned short*)nullptr);

    // ---- Final projection ----
    final_gemm<<<768, blk, 0, stream>>>(h1, linW, linb, out);
}